// Round 1
// 672.665 us; speedup vs baseline: 1.1313x; 1.1313x over previous
//
#include <hip/hip_runtime.h>
#include <cstddef>

// WITRAN 2D PSGMU encoder, MI355X — v5: fp16 single-pass MFMA.
// v4 used bf16-A + split-bf16-W (hi+lo) = 6 MFMA/kc. But A was plain bf16,
// so gate error was dominated by A's 2^-8 mantissa, not W. fp16 for BOTH
// A and W is strictly more accurate (2^-11 each) and halves the MFMA
// stream (3 MFMA/kc) and Wfrag size/traffic. Range-safe: |h|<1 (tanh*sig),
// x~N(0,1), |W|<=0.0625. fp32 accumulate + fp32 h carry unchanged.
// Launch-per-step kept (CP is the fastest barrier: grid barriers measured
// 30-38us/step in a prior session vs ~10us/step here).

namespace {
constexpr int H_   = 256;
constexpr int C_   = 32;
constexpr int B_   = 32;
constexpr int R_   = 24;
constexpr int LOR_ = 48;
constexpr int L_   = 71;
constexpr int N_   = 768;
constexpr int KH_  = 512;
constexpr int KT_  = 544;
constexpr int AST_ = 552;   // LDS A stride (elems)
}

typedef __attribute__((ext_vector_type(8))) _Float16       f16x8;
typedef __attribute__((ext_vector_type(8))) unsigned short u16x8;
typedef __attribute__((ext_vector_type(4))) float          f32x4;
typedef __attribute__((ext_vector_type(2))) float          f32x2;

__device__ __forceinline__ float fsig(float x)  { return 1.f / (1.f + __expf(-x)); }
__device__ __forceinline__ float ftanhf(float x){ float e = __expf(2.f * x); return 1.f - 2.f / (e + 1.f); }

// ---------------------------------------------------------------------------
// Prep 1: W -> fragment-native fp16 (layout identical to v4's verified map,
// minus the hi/lo pass dimension).
// Wfrag[((kc*96 + lt)*64 + lane)*8 + j8]; lt=kt*6+g; col j=g*256+kt*16+kl
// ---------------------------------------------------------------------------
__global__ __launch_bounds__(256) void prep_w(const float* __restrict__ W,
                                              _Float16* __restrict__ Wfrag) {
    int o = blockIdx.x * 256 + threadIdx.x;          // < 835,584
    int j8   = o & 7;
    int lane = (o >> 3) & 63;
    int rest = o >> 9;
    int lt   = rest % 96;
    int kc   = rest / 96;                            // < 17
    int n0 = lane & 15, quad = lane >> 4;
    int lg  = lt * 16 + n0;
    int kt  = lg / 96;
    int rem = lg % 96;
    int g  = rem >> 4, kl = rem & 15;
    int j  = g * 256 + kt * 16 + kl;
    int kg = kc * 32 + quad * 8 + j8;
    Wfrag[o] = (_Float16)W[j * KT_ + kg];
}

// ---------------------------------------------------------------------------
// Prep 2: all shifted x slices, fp16. xall[s][n][c], n=r*32+b, l=s-r.
// ---------------------------------------------------------------------------
__global__ __launch_bounds__(256) void prep_x(const float* __restrict__ inp,
                                              _Float16* __restrict__ xall) {
    int o = blockIdx.x * 256 + threadIdx.x;          // < 1,744,896
    int c = o & 31;
    int n = (o >> 5) % N_;
    int s = (o >> 5) / N_;
    int r = n >> 5, b = n & 31;
    int l = s - r;
    float v = 0.f;
    if (l >= 0 && l < LOR_) v = inp[((b * LOR_ + l) * R_ + r) * C_ + c];
    xall[o] = (_Float16)v;
}

// ---------------------------------------------------------------------------
// One step. 256 blocks: kt = bx&15, mc = bx>>4 (rows [mc*48, mc*48+48)).
// 6 waves, wave wv = gate group g.
// ---------------------------------------------------------------------------
__global__ __launch_bounds__(384, 2) void step_k(
    const _Float16* __restrict__ Wfrag,
    const _Float16* __restrict__ xall,
    const _Float16* __restrict__ hbc,
    const float*    __restrict__ hfc,
    _Float16*       __restrict__ hbn,
    float*          __restrict__ hfn,
    const float* __restrict__ Bp,
    float* __restrict__ out0, float* __restrict__ out1, float* __restrict__ out2,
    int s)
{
    __shared__ unsigned short As[48 * AST_];   // A tile: 48 rows x 544 (pad 552)
    __shared__ float Gt[48][104];              // gate tile 48m x 96l

    const int t    = threadIdx.x;
    const int wv   = t >> 6;                   // 0..5 = gate group g
    const int lane = t & 63;
    const int n0   = lane & 15;
    const int quad = lane >> 4;
    const int kt   = blockIdx.x & 15;
    const int mc   = blockIdx.x >> 4;

    // ---- stage A (h 48x512 + x 48x32) into LDS ------------------------------
#pragma unroll
    for (int it = 0; it < 8; ++it) {
        int q   = it * 384 + t;                // < 3072
        int row = q >> 6;
        int col = (q & 63) * 8;
        *(u16x8*)(void*)(&As[row * AST_ + col]) =
            *(const u16x8*)(const void*)((const unsigned short*)hbc +
                                         (size_t)(mc * 48 + row) * KH_ + col);
    }
    if (t < 192) {
        int row = t >> 2;
        int col = (t & 3) * 8;
        *(u16x8*)(void*)(&As[row * AST_ + 512 + col]) =
            *(const u16x8*)(const void*)((const unsigned short*)xall +
                                         (size_t)(s * N_ + mc * 48 + row) * C_ + col);
    }
    __syncthreads();

    // ---- GEMM: wave = gate g, 3 m-tiles x 16 gate cols ----------------------
    f32x4 acc[3];
#pragma unroll
    for (int mt = 0; mt < 3; ++mt) acc[mt] = (f32x4){0.f, 0.f, 0.f, 0.f};

#pragma unroll
    for (int kc = 0; kc < 17; ++kc) {
        f16x8 b = *(const f16x8*)(const void*)(
            Wfrag + ((size_t)(kc * 96 + kt * 6 + wv) * 64 + lane) * 8);
        f16x8 a[3];
#pragma unroll
        for (int mt = 0; mt < 3; ++mt)
            a[mt] = *(const f16x8*)(const void*)(
                &As[(mt * 16 + n0) * AST_ + kc * 32 + quad * 8]);
#pragma unroll
        for (int mt = 0; mt < 3; ++mt)
            acc[mt] = __builtin_amdgcn_mfma_f32_16x16x32_f16(a[mt], b, acc[mt], 0, 0, 0);
    }

    // D layout: col = lane&15 (gate col), row = quad*4 + reg (m)
#pragma unroll
    for (int mt = 0; mt < 3; ++mt)
#pragma unroll
        for (int reg = 0; reg < 4; ++reg)
            Gt[mt * 16 + quad * 4 + reg][wv * 16 + n0] = acc[mt][reg];

    __syncthreads();

    // ---- fused update: 48m x 16k, thread = 1 m-row x 2 k --------------------
    {
        const int mm = t >> 3;
        const int kp = (t & 7) * 2;
        const int n  = mc * 48 + mm;
        const int k  = kt * 16 + kp;
        const int r  = n >> 5, b = n & 31;
        const bool useb = (r <= s) && (s < R_);

        f32x2 gv[6];
#pragma unroll
        for (int g = 0; g < 6; ++g) {
            f32x2 v  = *(const f32x2*)(const void*)&Gt[mm][g * 16 + kp];
            f32x2 bp = *(const f32x2*)(const void*)(Bp + g * 256 + k);
            gv[g] = useb ? (v + bp) : v;
        }

        f32x2 hro = *(const f32x2*)(const void*)(hfc + (size_t)n * KH_ + k);
        f32x2 hco = *(const f32x2*)(const void*)(hfc + (size_t)n * KH_ + 256 + k);

        f32x2 hrv, hcv;
#pragma unroll
        for (int j = 0; j < 2; ++j) {
            float ur = fsig(gv[0][j]);
            float oR = fsig(gv[1][j]);
            float uc = fsig(gv[2][j]);
            float oc = fsig(gv[3][j]);
            float ir = ftanhf(gv[4][j]);
            float ic = ftanhf(gv[5][j]);
            hrv[j] = ftanhf((1.f - ur) * hro[j] + ur * ir) * oR;
            hcv[j] = ftanhf((1.f - uc) * hco[j] + uc * ic) * oc;
        }

        // trace output (write-only: non-temporal, keep L2 clean for W/h)
        float* o0 = out0 + ((size_t)n * L_ + s) * 512;
        __builtin_nontemporal_store(hrv, (f32x2*)(void*)(o0 + k));
        __builtin_nontemporal_store(hcv, (f32x2*)(void*)(o0 + 256 + k));

        int n2 = n + B_; if (n2 >= N_) n2 -= N_;
        *(f32x2*)(void*)(hfn + (size_t)n  * KH_ + k)       = hrv;
        *(f32x2*)(void*)(hfn + (size_t)n2 * KH_ + 256 + k) = hcv;

        _Float16 hr0 = (_Float16)hrv[0], hr1 = (_Float16)hrv[1];
        _Float16 hc0 = (_Float16)hcv[0], hc1 = (_Float16)hcv[1];
        _Float16* pr = hbn + (size_t)n  * KH_ + k;
        _Float16* pc = hbn + (size_t)n2 * KH_ + 256 + k;
        pr[0] = hr0; pr[1] = hr1;
        pc[0] = hc0; pc[1] = hc1;

        if (s >= LOR_ - 1 && r == s - (LOR_ - 1))
            __builtin_nontemporal_store(hrv, (f32x2*)(void*)(out2 + (size_t)(b * R_ + r) * H_ + k));
        if (r == R_ - 1 && s >= R_ - 1)
            __builtin_nontemporal_store(hcv, (f32x2*)(void*)(out1 + (size_t)(b * LOR_ + (s - (R_ - 1))) * H_ + k));
    }
}

// ---------------------------------------------------------------------------
extern "C" void kernel_launch(void* const* d_in, const int* in_sizes, int n_in,
                              void* d_out, int out_size, void* d_ws, size_t ws_size,
                              hipStream_t stream) {
    const float* inp = (const float*)d_in[0];
    const float* W   = (const float*)d_in[1];
    const float* Bp  = (const float*)d_in[2];

    float* out0 = (float*)d_out;
    float* out1 = out0 + (size_t)N_ * L_ * 512;
    float* out2 = out1 + (size_t)B_ * LOR_ * H_;

    char* ws = (char*)d_ws;
    _Float16* Wfrag = (_Float16*)(ws);                 // 1,671,168 B
    _Float16* xall  = (_Float16*)(ws + 1671168);       // 3,489,792 B
    _Float16* hbf0  = (_Float16*)(ws + 5160960);       //   786,432 B
    _Float16* hbf1  = (_Float16*)(ws + 5947392);       //   786,432 B
    float*    hf0   = (float*)(ws + 6733824);          // 1,572,864 B
    float*    hf1   = (float*)(ws + 8306688);          // 1,572,864 B

    (void)hipMemsetAsync(hbf0, 0, 786432, stream);
    (void)hipMemsetAsync(hf0,  0, 1572864, stream);

    prep_w<<<3264, 256, 0, stream>>>(W, Wfrag);
    prep_x<<<6816, 256, 0, stream>>>(inp, xall);

    for (int s = 0; s < L_; ++s) {
        const _Float16* hbc = (s & 1) ? hbf1 : hbf0;
        _Float16*       hbn = (s & 1) ? hbf0 : hbf1;
        const float*    hfc = (s & 1) ? hf1 : hf0;
        float*          hfn = (s & 1) ? hf0 : hf1;
        step_k<<<256, 384, 0, stream>>>(Wfrag, xall, hbc, hfc, hbn, hfn,
                                        Bp, out0, out1, out2, s);
    }
}